// Round 2
// baseline (1477.230 us; speedup 1.0000x reference)
//
#include <hip/hip_runtime.h>

// out0 = cumsum(z, axis=0), z fp32 [8192, 64, 128] -> 8192 rows x 8192 contiguous cols.
// out1 = previous_loss (1 float) at d_out[8192*8192].

constexpr int NROWS = 8192;
constexpr int NCOLS = 8192;
constexpr int NCOL4 = NCOLS / 4;     // 2048 float4 per row
constexpr int TPB   = 256;

// ---------- single-pass decoupled lookback ----------
constexpr int R     = 32;            // rows per chunk
constexpr int K     = NROWS / R;     // 256 chunks
constexpr int TILE4 = TPB;           // 256 float4 cols per tile (1 per thread)
constexpr int NTILE = NCOL4 / TILE4; // 8 independent scan chains
constexpr int NBLK  = K * NTILE;     // 2048 blocks

__device__ __forceinline__ void f4add(float4& a, const float4 b) {
    a.x += b.x; a.y += b.y; a.z += b.z; a.w += b.w;
}

__global__ __launch_bounds__(TPB) void k_lookback(
    const float4* __restrict__ z, float4* __restrict__ out,
    float4* __restrict__ agg, float4* __restrict__ incl,
    unsigned int* __restrict__ flags,
    const float* __restrict__ prev, float* __restrict__ out_tail)
{
    const int bid   = blockIdx.x;
    const int chunk = bid / NTILE;       // chunk-major: consecutive bids = same chunk
    const int tile  = bid % NTILE;
    const int tid   = threadIdx.x;

    if (bid == 0 && tid == 0) out_tail[0] = prev[0];

    const int c4 = tile * TILE4 + tid;
    const float4* p = z + (size_t)chunk * R * NCOL4 + c4;

    // load chunk, running cumsum in registers
    float4 v[R];
    float4 run = make_float4(0.f, 0.f, 0.f, 0.f);
    #pragma unroll
    for (int r = 0; r < R; ++r) {
        float4 t = p[(size_t)r * NCOL4];
        f4add(run, t);
        v[r] = run;
    }
    // run == this block's per-column aggregate

    float4 prefix = make_float4(0.f, 0.f, 0.f, 0.f);
    if (chunk == 0) {
        incl[(size_t)bid * TILE4 + tid] = run;
        __threadfence();
        __syncthreads();
        if (tid == 0)
            __hip_atomic_store(&flags[bid], 2u, __ATOMIC_RELEASE, __HIP_MEMORY_SCOPE_AGENT);
    } else {
        agg[(size_t)bid * TILE4 + tid] = run;
        __threadfence();
        __syncthreads();
        if (tid == 0)
            __hip_atomic_store(&flags[bid], 1u, __ATOMIC_RELEASE, __HIP_MEMORY_SCOPE_AGENT);

        // decoupled lookback over predecessors in this tile's chain
        int pb = bid - NTILE;
        for (;;) {
            unsigned int f;
            while ((f = __hip_atomic_load(&flags[pb], __ATOMIC_RELAXED,
                                          __HIP_MEMORY_SCOPE_AGENT)) == 0u) {
                __builtin_amdgcn_s_sleep(2);
            }
            __builtin_amdgcn_fence(__ATOMIC_ACQUIRE, "agent");
            if (f == 2u) {                                   // inclusive prefix: done
                f4add(prefix, incl[(size_t)pb * TILE4 + tid]);
                break;
            } else {                                         // aggregate: keep walking
                f4add(prefix, agg[(size_t)pb * TILE4 + tid]);
                pb -= NTILE;
            }
        }

        // publish inclusive prefix for successors
        float4 inc = run;
        f4add(inc, prefix);
        incl[(size_t)bid * TILE4 + tid] = inc;
        __threadfence();
        __syncthreads();
        if (tid == 0)
            __hip_atomic_store(&flags[bid], 2u, __ATOMIC_RELEASE, __HIP_MEMORY_SCOPE_AGENT);
    }

    // add exclusive prefix, write out
    float4* q = out + (size_t)chunk * R * NCOL4 + c4;
    #pragma unroll
    for (int r = 0; r < R; ++r) {
        float4 t = v[r];
        f4add(t, prefix);
        q[(size_t)r * NCOL4] = t;
    }
}

// ---------- fallback 3-pass (known-good from round 1) ----------
constexpr int KCH = 128;
constexpr int RR  = NROWS / KCH;
constexpr int CT  = NCOL4 / TPB;

__global__ __launch_bounds__(TPB) void k_partial(const float4* __restrict__ z,
                                                 float4* __restrict__ part) {
    const int tile  = blockIdx.x & (CT - 1);
    const int chunk = blockIdx.x >> 3;
    const int c4    = tile * TPB + threadIdx.x;
    const float4* p = z + (size_t)chunk * RR * NCOL4 + c4;
    float4 a = make_float4(0.f, 0.f, 0.f, 0.f);
    #pragma unroll 8
    for (int r = 0; r < RR; ++r) f4add(a, p[(size_t)r * NCOL4]);
    part[(size_t)chunk * NCOL4 + c4] = a;
}

__global__ __launch_bounds__(TPB) void k_scan(float* __restrict__ part,
                                              const float* __restrict__ prev,
                                              float* __restrict__ out_tail) {
    const int c = blockIdx.x * TPB + threadIdx.x;
    float run = 0.f;
    #pragma unroll 4
    for (int k = 0; k < KCH; ++k) {
        const size_t i = (size_t)k * NCOLS + c;
        float v = part[i];
        part[i] = run;
        run += v;
    }
    if (blockIdx.x == 0 && threadIdx.x == 0) out_tail[0] = prev[0];
}

__global__ __launch_bounds__(TPB) void k_apply(const float4* __restrict__ z,
                                               const float4* __restrict__ part,
                                               float4* __restrict__ out) {
    const int tile  = blockIdx.x & (CT - 1);
    const int chunk = blockIdx.x >> 3;
    const int c4    = tile * TPB + threadIdx.x;
    float4 a = part[(size_t)chunk * NCOL4 + c4];
    const float4* p = z + (size_t)chunk * RR * NCOL4 + c4;
    float4*       q = out + (size_t)chunk * RR * NCOL4 + c4;
    #pragma unroll 4
    for (int r = 0; r < RR; ++r) {
        float4 t = p[(size_t)r * NCOL4];
        f4add(a, t);
        q[(size_t)r * NCOL4] = a;
    }
}

extern "C" void kernel_launch(void* const* d_in, const int* in_sizes, int n_in,
                              void* d_out, int out_size, void* d_ws, size_t ws_size,
                              hipStream_t stream) {
    const float4* z    = (const float4*)d_in[0];
    const float*  prev = (const float*)d_in[1];
    float*        out  = (float*)d_out;
    float*        tail = out + (size_t)NROWS * NCOLS;

    const size_t payload = (size_t)NBLK * TILE4 * sizeof(float4);  // 8 MiB each
    const size_t need    = 2 * payload + NBLK * sizeof(unsigned int);

    if (ws_size >= need) {
        float4* agg   = (float4*)d_ws;
        float4* incl  = agg + (size_t)NBLK * TILE4;
        unsigned int* flags = (unsigned int*)((char*)d_ws + 2 * payload);
        hipMemsetAsync(flags, 0, NBLK * sizeof(unsigned int), stream);
        k_lookback<<<NBLK, TPB, 0, stream>>>(z, (float4*)out, agg, incl, flags, prev, tail);
    } else {
        float* part = (float*)d_ws;  // 4 MiB
        k_partial<<<KCH * CT, TPB, 0, stream>>>(z, (float4*)part);
        k_scan<<<NCOLS / TPB, TPB, 0, stream>>>(part, prev, tail);
        k_apply<<<KCH * CT, TPB, 0, stream>>>(z, (const float4*)part, (float4*)out);
    }
}

// Round 3
// 136.546 us; speedup vs baseline: 10.8185x; 10.8185x over previous
//
#include <hip/hip_runtime.h>

// out0 = cumsum(z, axis=0), z fp32 [8192, 64, 128] -> 8192 rows x 8192 contiguous cols.
// out1 = previous_loss (1 float) at d_out[8192*8192].
//
// 3-pass chunked scan. Pass 3 runs chunks in REVERSE order (last chunk read by
// pass 1 is re-read first -> minimal L3 reuse distance) and writes the output
// with nontemporal stores so the write stream doesn't evict z from the 256 MiB
// Infinity Cache.

typedef float f4 __attribute__((ext_vector_type(4)));

constexpr int NROWS = 8192;
constexpr int NCOLS = 8192;
constexpr int NCOL4 = NCOLS / 4;     // 2048 float4 per row
constexpr int TPB   = 256;
constexpr int KCH   = 128;           // row chunks
constexpr int RR    = NROWS / KCH;   // 64 rows per chunk
constexpr int CT    = NCOL4 / TPB;   // 8 column tiles

// Pass 1: per-column sums of each row-chunk -> part[KCH][NCOLS]
__global__ __launch_bounds__(TPB) void k_partial(const f4* __restrict__ z,
                                                 f4* __restrict__ part) {
    const int tile  = blockIdx.x & (CT - 1);
    const int chunk = blockIdx.x >> 3;
    const int c4    = tile * TPB + threadIdx.x;
    const f4* p = z + (size_t)chunk * RR * NCOL4 + c4;
    f4 a = (f4)0.f;
    #pragma unroll 8
    for (int r = 0; r < RR; ++r) a += p[(size_t)r * NCOL4];
    part[(size_t)chunk * NCOL4 + c4] = a;
}

// Pass 2: in-place serial EXCLUSIVE scan over the KCH chunk sums, per column.
// Loads within each unroll-16 group are independent -> deep pipelining.
__global__ __launch_bounds__(TPB) void k_scan(float* __restrict__ part,
                                              const float* __restrict__ prev,
                                              float* __restrict__ out_tail) {
    const int c = blockIdx.x * TPB + threadIdx.x; // 0..8191
    float run = 0.f;
    #pragma unroll 16
    for (int k = 0; k < KCH; ++k) {
        const size_t i = (size_t)k * NCOLS + c;
        float v = part[i];
        part[i] = run;
        run += v;
    }
    if (blockIdx.x == 0 && threadIdx.x == 0) out_tail[0] = prev[0];
}

// Pass 3: re-read z (reverse chunk order; mostly L3-resident), add exclusive
// chunk prefix, write inclusive cumsum with nontemporal stores.
__global__ __launch_bounds__(TPB) void k_apply(const f4* __restrict__ z,
                                               const f4* __restrict__ part,
                                               f4* __restrict__ out) {
    const int tile  = blockIdx.x & (CT - 1);
    const int chunk = KCH - 1 - (blockIdx.x >> 3);   // reversed
    const int c4    = tile * TPB + threadIdx.x;
    f4 a = part[(size_t)chunk * NCOL4 + c4];
    const f4* p = z   + (size_t)chunk * RR * NCOL4 + c4;
    f4*       q = out + (size_t)chunk * RR * NCOL4 + c4;
    #pragma unroll 4
    for (int r = 0; r < RR; ++r) {
        a += p[(size_t)r * NCOL4];
        __builtin_nontemporal_store(a, &q[(size_t)r * NCOL4]);
    }
}

extern "C" void kernel_launch(void* const* d_in, const int* in_sizes, int n_in,
                              void* d_out, int out_size, void* d_ws, size_t ws_size,
                              hipStream_t stream) {
    const f4*    z    = (const f4*)d_in[0];
    const float* prev = (const float*)d_in[1];
    float*       out  = (float*)d_out;
    float*       part = (float*)d_ws;   // KCH*NCOLS floats = 4 MiB
    float*       tail = out + (size_t)NROWS * NCOLS;

    k_partial<<<KCH * CT, TPB, 0, stream>>>(z, (f4*)part);
    k_scan<<<NCOLS / TPB, TPB, 0, stream>>>(part, prev, tail);
    k_apply<<<KCH * CT, TPB, 0, stream>>>(z, (const f4*)part, (f4*)out);
}

// Round 4
// 136.038 us; speedup vs baseline: 10.8590x; 1.0037x over previous
//
#include <hip/hip_runtime.h>
#include <hip/hip_cooperative_groups.h>

namespace cg = cooperative_groups;

// out0 = cumsum(z, axis=0), z fp32 [8192, 64, 128] -> 8192 rows x 8192 contiguous cols.
// out1 = previous_loss (1 float) at d_out[8192*8192].
//
// Fused single-pass: z slice held in REGISTERS across two grid-wide syncs, so z
// is read from HBM exactly once (vs twice in the 3-pass). 2048 blocks x 256 thr
// = 32 waves/CU, all co-resident (VGPR capped at 256 by __launch_bounds__).

typedef float f4 __attribute__((ext_vector_type(4)));

constexpr int NROWS = 8192;
constexpr int NCOLS = 8192;
constexpr int NCOL4 = NCOLS / 4;     // 2048 float4 per row
constexpr int TPB   = 256;

// fused config: 256 chunks x 32 rows, 8 column tiles
constexpr int FK    = 256;
constexpr int FR    = NROWS / FK;    // 32 rows per chunk -> 32 float4 = 128 VGPRs/thread
constexpr int FT    = NCOL4 / TPB;   // 8 tiles
constexpr int FGRID = FK * FT;       // 2048 blocks

__global__ __launch_bounds__(TPB, 8) void k_fused(
    const f4* __restrict__ z, f4* __restrict__ out, f4* __restrict__ agg,
    const float* __restrict__ prev, float* __restrict__ out_tail)
{
    const int bid   = blockIdx.x;
    const int chunk = bid >> 3;          // / FT
    const int tile  = bid & (FT - 1);
    const int tid   = threadIdx.x;
    const int c4    = tile * TPB + tid;

    if (bid == 0 && tid == 0) out_tail[0] = prev[0];

    // Phase A: load slice, running cumsum in registers, publish chunk aggregate.
    const f4* p = z + (size_t)chunk * FR * NCOL4 + c4;
    f4 v[FR];
    f4 run = (f4)0.f;
    #pragma unroll
    for (int r = 0; r < FR; ++r) { run += p[(size_t)r * NCOL4]; v[r] = run; }
    agg[(size_t)chunk * NCOL4 + c4] = run;

    __threadfence();
    cg::this_grid().sync();

    // Phase B: 8 blocks scan the 256 chunk aggregates per float4-column, in place.
    if (bid < FT) {
        const int col = bid * TPB + tid;
        f4 s = (f4)0.f;
        #pragma unroll 8
        for (int k = 0; k < FK; ++k) {
            const size_t i = (size_t)k * NCOL4 + col;
            f4 t = agg[i]; agg[i] = s; s += t;
        }
    }
    __threadfence();
    cg::this_grid().sync();

    // Phase C: add exclusive chunk prefix to register-held values, stream out.
    const f4 prefix = agg[(size_t)chunk * NCOL4 + c4];
    f4* q = out + (size_t)chunk * FR * NCOL4 + c4;
    #pragma unroll
    for (int r = 0; r < FR; ++r) q[(size_t)r * NCOL4] = v[r] + prefix;
}

// ---------- fallback 3-pass (known-good, 136 us) ----------
constexpr int KCH = 128;
constexpr int RR  = NROWS / KCH;
constexpr int CT  = NCOL4 / TPB;

__global__ __launch_bounds__(TPB) void k_partial(const f4* __restrict__ z,
                                                 f4* __restrict__ part) {
    const int tile  = blockIdx.x & (CT - 1);
    const int chunk = blockIdx.x >> 3;
    const int c4    = tile * TPB + threadIdx.x;
    const f4* p = z + (size_t)chunk * RR * NCOL4 + c4;
    f4 a = (f4)0.f;
    #pragma unroll 8
    for (int r = 0; r < RR; ++r) a += p[(size_t)r * NCOL4];
    part[(size_t)chunk * NCOL4 + c4] = a;
}

__global__ __launch_bounds__(TPB) void k_scan(float* __restrict__ part,
                                              const float* __restrict__ prev,
                                              float* __restrict__ out_tail) {
    const int c = blockIdx.x * TPB + threadIdx.x;
    float run = 0.f;
    #pragma unroll 16
    for (int k = 0; k < KCH; ++k) {
        const size_t i = (size_t)k * NCOLS + c;
        float v = part[i];
        part[i] = run;
        run += v;
    }
    if (blockIdx.x == 0 && threadIdx.x == 0) out_tail[0] = prev[0];
}

__global__ __launch_bounds__(TPB) void k_apply(const f4* __restrict__ z,
                                               const f4* __restrict__ part,
                                               f4* __restrict__ out) {
    const int tile  = blockIdx.x & (CT - 1);
    const int chunk = KCH - 1 - (blockIdx.x >> 3);
    const int c4    = tile * TPB + threadIdx.x;
    f4 a = part[(size_t)chunk * NCOL4 + c4];
    const f4* p = z   + (size_t)chunk * RR * NCOL4 + c4;
    f4*       q = out + (size_t)chunk * RR * NCOL4 + c4;
    #pragma unroll 4
    for (int r = 0; r < RR; ++r) {
        a += p[(size_t)r * NCOL4];
        __builtin_nontemporal_store(a, &q[(size_t)r * NCOL4]);
    }
}

extern "C" void kernel_launch(void* const* d_in, const int* in_sizes, int n_in,
                              void* d_out, int out_size, void* d_ws, size_t ws_size,
                              hipStream_t stream) {
    const f4*    z    = (const f4*)d_in[0];
    const float* prev = (const float*)d_in[1];
    float*       out  = (float*)d_out;
    float*       tail = out + (size_t)NROWS * NCOLS;

    const size_t agg_bytes = (size_t)FK * NCOL4 * sizeof(f4);   // 8 MiB

    // Cooperative path requires full co-residency (8 blocks/CU) and ws for agg.
    int blocksPerCU = 0;
    hipError_t qe = hipOccupancyMaxActiveBlocksPerMultiprocessor(
        &blocksPerCU, (const void*)k_fused, TPB, 0);
    const bool coop_ok = (qe == hipSuccess) && (blocksPerCU >= FGRID / 256) &&
                         (ws_size >= agg_bytes);

    if (coop_ok) {
        f4* agg = (f4*)d_ws;
        f4* outv = (f4*)out;
        void* args[] = { (void*)&z, (void*)&outv, (void*)&agg,
                         (void*)&prev, (void*)&tail };
        hipError_t le = hipLaunchCooperativeKernel((const void*)k_fused,
                                                   dim3(FGRID), dim3(TPB),
                                                   args, 0, stream);
        if (le == hipSuccess) return;
    }

    // fallback: proven 3-pass
    float* part = (float*)d_ws;
    k_partial<<<KCH * CT, TPB, 0, stream>>>(z, (f4*)part);
    k_scan<<<NCOLS / TPB, TPB, 0, stream>>>(part, prev, tail);
    k_apply<<<KCH * CT, TPB, 0, stream>>>(z, (const f4*)part, (f4*)out);
}